// Round 11
// baseline (32.351 us; speedup 1.0000x reference)
//
#include <hip/hip_runtime.h>
#include <math.h>

// Problem constants: D=2048, K=4096, C=1000, W=4096
constexpr int KN = 4096;
constexpr int DN = 2048;
constexpr int CN = 1000;
constexpr int WN = 4096;

// Butterfly reductions — result valid in ALL lanes.
__device__ __forceinline__ float waveSum(float v) {
#pragma unroll
    for (int o = 32; o > 0; o >>= 1) v += __shfl_xor(v, o, 64);
    return v;
}
__device__ __forceinline__ float waveMax(float v) {
#pragma unroll
    for (int o = 32; o > 0; o >>= 1) v = fmaxf(v, __shfl_xor(v, o, 64));
    return v;
}

// Stage 1: per-wave rows, no block barriers (R7-identical; 32 waves/CU).
constexpr int S1_DIST_BLOCKS = KN / 4;   // 1024
constexpr int S1_CE_BLOCKS   = KN / 4;   // 1024

__global__ __launch_bounds__(256) void stage1_kernel(
    const float* __restrict__ deep, const float* __restrict__ nmat,
    const float* __restrict__ cls, const int* __restrict__ target,
    float* __restrict__ d_arr, float* __restrict__ ce_arr)
{
    const int b    = blockIdx.x;
    const int tid  = threadIdx.x;
    const int wv   = tid >> 6;
    const int lane = tid & 63;

    if (b < S1_DIST_BLOCKS) {
        // ---- distance row: 512 float4, 8 per lane ----
        const int row = b * 4 + wv;
        const float4* nrow = (const float4*)(nmat + (size_t)row * DN);
        const float4* df   = (const float4*)deep;
        float acc = 0.f;
#pragma unroll
        for (int c = 0; c < 8; ++c) {
            const int i = lane + 64 * c;
            const float4 a = df[i];
            const float4 x = nrow[i];
            const float e0 = a.x - x.x, e1 = a.y - x.y, e2 = a.z - x.z, e3 = a.w - x.w;
            acc += e0 * e0 + e1 * e1 + e2 * e2 + e3 * e3;
        }
        acc = waveSum(acc);
        if (lane == 0) d_arr[row] = sqrtf(acc);
    } else {
        // ---- CE row: 250 float4, <=4 per lane, padded with -inf ----
        const int row = (b - S1_DIST_BLOCKS) * 4 + wv;
        const float4* x4 = (const float4*)(cls + (size_t)row * CN);
        float4 v[4];
#pragma unroll
        for (int j = 0; j < 4; ++j) {
            const int i = lane + 64 * j;
            v[j] = (i < CN / 4) ? x4[i]
                                : make_float4(-INFINITY, -INFINITY, -INFINITY, -INFINITY);
        }
        float mx = -INFINITY;
#pragma unroll
        for (int j = 0; j < 4; ++j)
            mx = fmaxf(mx, fmaxf(fmaxf(v[j].x, v[j].y), fmaxf(v[j].z, v[j].w)));
        const float m = waveMax(mx);
        float s = 0.f;
#pragma unroll
        for (int j = 0; j < 4; ++j)    // exp(-inf - m) == 0, pads vanish
            s += __expf(v[j].x - m) + __expf(v[j].y - m)
               + __expf(v[j].z - m) + __expf(v[j].w - m);
        s = waveSum(s);
        if (lane == 0)
            ce_arr[row] = m + __logf(s) - cls[(size_t)row * CN + target[0]];
    }
}

// Stage 2 (R11): 1024 blocks x 512 threads (8 waves). A WAVE PAIR splits each
// w-row (half-row per wave) -> 4 rows/block, 8192 waves total = 32 waves/CU
// (vs 16 in R7 — the MLP fix). __launch_bounds__(512,8) caps VGPR at 64 so
// 8 waves/SIMD fit. Halves combined in LDS BEFORE the per-row division.
// No-max softmax exact-safe: s = -w*d in (-70, 0].
constexpr int S2_BLOCK_THREADS = 512;
constexpr int S2_ROWS_PER_BLK  = 4;
constexpr int S2_BLOCKS        = WN / S2_ROWS_PER_BLK;    // 1024

__global__ __launch_bounds__(S2_BLOCK_THREADS, 8) void stage2_kernel(
    const float* __restrict__ wmat, const float* __restrict__ d_arr,
    const float* __restrict__ ce_arr, float* __restrict__ part)
{
    __shared__ float sred[8][3];
    const int tid  = threadIdx.x;
    const int wv   = tid >> 6;        // 0..7
    const int lane = tid & 63;
    const int rloc = wv >> 1;         // 0..3: row within block
    const int half = wv & 1;          // 0/1: which half of the row
    const int row  = blockIdx.x * S2_ROWS_PER_BLK + rloc;

    const float4* wrow = (const float4*)(wmat + (size_t)row * KN);
    const float4* d4   = (const float4*)d_arr;
    const float4* c4   = (const float4*)ce_arr;

    const int base = half * 512 + lane;   // this wave's half: 8 float4 strides

    float4 wa[4], wb[4];
#pragma unroll
    for (int j = 0; j < 4; ++j) wa[j] = wrow[base + 64 * j];
    // prefetch second batch immediately (stays in flight under compute)
#pragma unroll
    for (int j = 0; j < 4; ++j) wb[j] = wrow[base + 64 * (4 + j)];

    float es = 0.f, ec = 0.f, fs = 0.f;
#pragma unroll
    for (int j = 0; j < 4; ++j) {
        const int i = base + 64 * j;
        const float4 dv = d4[i];
        const float4 cv = c4[i];
        const float4 a  = wa[j];
        float t, e;
        t = a.x * dv.x; fs += t; e = __expf(-t); es += e; ec += e * cv.x;
        t = a.y * dv.y; fs += t; e = __expf(-t); es += e; ec += e * cv.y;
        t = a.z * dv.z; fs += t; e = __expf(-t); es += e; ec += e * cv.z;
        t = a.w * dv.w; fs += t; e = __expf(-t); es += e; ec += e * cv.w;
    }
#pragma unroll
    for (int j = 0; j < 4; ++j) {
        const int i = base + 64 * (4 + j);
        const float4 dv = d4[i];
        const float4 cv = c4[i];
        const float4 a  = wb[j];
        float t, e;
        t = a.x * dv.x; fs += t; e = __expf(-t); es += e; ec += e * cv.x;
        t = a.y * dv.y; fs += t; e = __expf(-t); es += e; ec += e * cv.y;
        t = a.z * dv.z; fs += t; e = __expf(-t); es += e; ec += e * cv.z;
        t = a.w * dv.w; fs += t; e = __expf(-t); es += e; ec += e * cv.w;
    }

    es = waveSum(es);  ec = waveSum(ec);  fs = waveSum(fs);
    if (lane == 0) { sred[wv][0] = es; sred[wv][1] = ec; sred[wv][2] = fs; }
    __syncthreads();

    if (tid == 0) {
        float acc = 0.f;
#pragma unroll
        for (int r = 0; r < 4; ++r) {
            const float tes = sred[2 * r][0] + sred[2 * r + 1][0];
            const float tec = sred[2 * r][1] + sred[2 * r + 1][1];
            const float tfs = sred[2 * r][2] + sred[2 * r + 1][2];
            acc += tec / tes + tfs;
        }
        part[blockIdx.x] = acc;      // plain store — no atomic
    }
}

// Stage 3: one block, deterministic reduce of the 1024 block partials.
__global__ __launch_bounds__(512) void stage3_kernel(
    const float* __restrict__ part, float* __restrict__ out)
{
    __shared__ float red[8];
    const int tid  = threadIdx.x;
    const int wv   = tid >> 6;
    const int lane = tid & 63;
    float v = part[tid] + part[tid + 512];
    v = waveSum(v);
    if (lane == 0) red[wv] = v;
    __syncthreads();
    if (tid == 0) {
        float acc = 0.f;
#pragma unroll
        for (int j = 0; j < 8; ++j) acc += red[j];
        out[0] = acc;
    }
}

extern "C" void kernel_launch(void* const* d_in, const int* in_sizes, int n_in,
                              void* d_out, int out_size, void* d_ws, size_t ws_size,
                              hipStream_t stream) {
    const float* deep   = (const float*)d_in[0];   // [1, D]
    const float* cls    = (const float*)d_in[1];   // [K, C]
    const int*   target = (const int*)d_in[2];     // [1]
    const float* nmat   = (const float*)d_in[3];   // [K, D]
    const float* wmat   = (const float*)d_in[4];   // [W, K]

    float* ws     = (float*)d_ws;
    float* d_arr  = ws;            // [K]
    float* ce_arr = ws + KN;       // [K]
    float* part   = ws + 2 * KN;   // [1024]

    stage1_kernel<<<S1_DIST_BLOCKS + S1_CE_BLOCKS, 256, 0, stream>>>(
        deep, nmat, cls, target, d_arr, ce_arr);
    stage2_kernel<<<S2_BLOCKS, S2_BLOCK_THREADS, 0, stream>>>(
        wmat, d_arr, ce_arr, part);
    stage3_kernel<<<1, 512, 0, stream>>>(part, (float*)d_out);
}